// Round 13
// baseline (147.628 us; speedup 1.0000x reference)
//
#include <hip/hip_runtime.h>
#include <hip/hip_bf16.h>
#include <math.h>
#include <stdint.h>

#define HC 4
#define DIM 16384                  // hc*hidden
#define MIXN 24
#define NROWS 8192                 // B*S
#define KSPLIT 16                  // k-slices
#define KSL (DIM / KSPLIT)         // 1024 k per slice
#define NSTEPS (KSL / 32)          // 32 MFMA k-steps per slice
#define NSTREAM 32                 // row streams
#define ROWS_PER_STREAM (NROWS / NSTREAM)   // 256
#define THREADS1 512
#define NWAVE 8
#define ROWS_PER_BITER (NWAVE * 16)         // 128 rows per block-iteration
#define NITER (ROWS_PER_STREAM / ROWS_PER_BITER)  // 2
#define HC_EPS 1e-5f
#define NORM_EPS 1e-6f

#define PRE_OFF 0
#define POST_OFF (NROWS * HC)
#define COMB_OFF (2 * NROWS * HC)

typedef float f32x4 __attribute__((ext_vector_type(4)));
typedef float accf4 __attribute__((ext_vector_type(4)));
typedef short bf16x8 __attribute__((ext_vector_type(8)));

__device__ __forceinline__ short f2bf(float x) {
    union { __hip_bfloat16 h; short s; } u;
    u.h = __float2bfloat16(x);
    return u.s;
}

// ---------------- kernel 1: split-K partial GEMM + ssq ----------------
// fn lives in LDS as bf16 MFMA B-fragments (zero global fn traffic in the
// main loop). ssq comes from the DIAGONAL of mfma(af, af, acc): row r dot
// row r = sum(x^2) -- moves the RMS reduction from the VALU to the idle
// MFMA pipe (rounding of bf16 is to-nearest -> bias ~3e-5 relative).
__global__ __launch_bounds__(THREADS1) void hyper_k1(
    const float* __restrict__ hs,   // [NROWS][DIM]
    const float* __restrict__ fn,   // [MIXN][DIM]
    float* __restrict__ ws)         // [512*16][16][25] partials
{
    const int tid  = threadIdx.x;
    const int wave = tid >> 6;
    const int lane = tid & 63;
    const int l15  = lane & 15;
    const int kg   = lane >> 4;
    const int ks     = blockIdx.x & (KSPLIT - 1);
    const int stream = blockIdx.x >> 4;

    // [tile 0|1][step][lane*8 bf16] ; tile0 = fn cols 0-15, tile1 = cols 8-23
    __shared__ __align__(16) short s_fn[2][NSTEPS][64 * 8];   // 64 KB

    // ---- fast fill: one bf16x8 octet per thread-pass ----
    // octet (tile, c, s, kg): read fn[col][ks*KSL + s*32 + kg*8 .. +7],
    // write s_fn[tile][s][(kg*16+c)*8]. 4096 octets / 512 thr = 8 passes.
    // Consecutive tids walk (kg, s) within one col -> coalesced 4 KB reads.
    #pragma unroll 1
    for (int p = 0; p < 8; ++p) {
        const int idx  = p * THREADS1 + tid;
        const int kgf  = idx & 3;
        const int s    = (idx >> 2) & 31;
        const int c    = (idx >> 7) & 15;
        const int tile = idx >> 11;
        const int col  = tile ? (c + 8) : c;
        const float* g = fn + (size_t)col * DIM + ks * KSL + s * 32 + kgf * 8;
        const f32x4 v0 = *(const f32x4*)g;
        const f32x4 v1 = *(const f32x4*)(g + 4);
        bf16x8 b = { f2bf(v0.x), f2bf(v0.y), f2bf(v0.z), f2bf(v0.w),
                     f2bf(v1.x), f2bf(v1.y), f2bf(v1.z), f2bf(v1.w) };
        *(bf16x8*)&s_fn[tile][s][(kgf * 16 + c) * 8] = b;
    }
    __syncthreads();

    #pragma unroll 1
    for (int it = 0; it < NITER; ++it) {
        const int rowbase = stream * ROWS_PER_STREAM + it * ROWS_PER_BITER + wave * 16;
        const float* abase = hs + (size_t)(rowbase + l15) * DIM + ks * KSL + kg * 8;

        accf4 acc0 = {0.f, 0.f, 0.f, 0.f};   // mix cols 0-15
        accf4 acc1 = {0.f, 0.f, 0.f, 0.f};   // mix cols 16-23 (tile cols 8-23)
        accf4 accS = {0.f, 0.f, 0.f, 0.f};   // A.A^T -> diag = ssq

        f32x4 A0, A1, B0, B1, C0, C1, D0, D1;   // depth-4 prefetch ring

#define ALD(Pa, Pb, S) do { \
    const float* _a = abase + (size_t)(S) * 32; \
    Pa = *(const f32x4*)_a; Pb = *(const f32x4*)(_a + 4); \
} while (0)

#define ACP(Pa, Pb, S) do { \
    bf16x8 af = { f2bf(Pa.x), f2bf(Pa.y), f2bf(Pa.z), f2bf(Pa.w), \
                  f2bf(Pb.x), f2bf(Pb.y), f2bf(Pb.z), f2bf(Pb.w) }; \
    const bf16x8 b0 = *(const bf16x8*)&s_fn[0][S][lane * 8]; \
    const bf16x8 b1 = *(const bf16x8*)&s_fn[1][S][lane * 8]; \
    acc0 = __builtin_amdgcn_mfma_f32_16x16x32_bf16(af, b0, acc0, 0, 0, 0); \
    acc1 = __builtin_amdgcn_mfma_f32_16x16x32_bf16(af, b1, acc1, 0, 0, 0); \
    accS = __builtin_amdgcn_mfma_f32_16x16x32_bf16(af, af, accS, 0, 0, 0); \
} while (0)

        ALD(A0, A1, 0); ALD(B0, B1, 1); ALD(C0, C1, 2); ALD(D0, D1, 3);
        #pragma unroll 1
        for (int s = 0; s < NSTEPS; s += 4) {
            ACP(A0, A1, s);     if (s + 4 < NSTEPS) ALD(A0, A1, s + 4);
            ACP(B0, B1, s + 1); if (s + 5 < NSTEPS) ALD(B0, B1, s + 5);
            ACP(C0, C1, s + 2); if (s + 6 < NSTEPS) ALD(C0, C1, s + 6);
            ACP(D0, D1, s + 3); if (s + 7 < NSTEPS) ALD(D0, D1, s + 7);
        }
#undef ALD
#undef ACP

        // partial writeout; C layout validated in R11: col=lane&15, row=kg*4+i
        const int rt = rowbase >> 4;                       // global rowtile 0..511
        float* w = ws + (size_t)(rt * KSPLIT + ks) * (16 * 25);
        #pragma unroll
        for (int i = 0; i < 4; ++i)
            w[(kg * 4 + i) * 25 + l15] = acc0[i];          // cols 0-15
        if (l15 >= 8) {
            #pragma unroll
            for (int i = 0; i < 4; ++i)
                w[(kg * 4 + i) * 25 + l15 + 8] = acc1[i];  // cols 16-23
        }
        // ssq: diagonal of accS lives where row (kg*4+i) == col (l15)
        #pragma unroll
        for (int i = 0; i < 4; ++i)
            if (l15 == kg * 4 + i) w[l15 * 25 + 24] = accS[i];
    }
}

// ---------------- kernel 2: reduce k-slices + epilogue ----------------
__global__ __launch_bounds__(256) void hyper_k2(
    const float* __restrict__ ws,
    const float* __restrict__ base,
    const float* __restrict__ scale,
    float* __restrict__ out)
{
    const int r  = blockIdx.x * 256 + threadIdx.x;   // row 0..8191
    const int rt = r >> 4, rr = r & 15;

    float v[25];
    #pragma unroll
    for (int c = 0; c < 25; ++c) v[c] = 0.f;
    #pragma unroll 1
    for (int ks = 0; ks < KSPLIT; ++ks) {
        const float* w = ws + (size_t)(rt * KSPLIT + ks) * (16 * 25) + rr * 25;
        #pragma unroll
        for (int c = 0; c < 25; ++c) v[c] += w[c];
    }

    const float rs = 1.0f / sqrtf(v[24] * (1.0f / (float)DIM) + NORM_EPS);
    const float s0 = scale[0], s1 = scale[1], s2 = scale[2];

    #pragma unroll
    for (int i = 0; i < HC; ++i) {
        const float z = v[i] * rs * s0 + base[i];
        out[PRE_OFF + r * HC + i] = 1.0f / (1.0f + expf(-z)) + HC_EPS;
    }
    #pragma unroll
    for (int i = 0; i < HC; ++i) {
        const float z = v[HC + i] * rs * s1 + base[HC + i];
        out[POST_OFF + r * HC + i] = 2.0f / (1.0f + expf(-z));
    }

    float c[HC][HC];
    #pragma unroll
    for (int i = 0; i < HC; ++i) {
        float l[HC];
        #pragma unroll
        for (int j = 0; j < HC; ++j)
            l[j] = v[2 * HC + i * HC + j] * rs * s2 + base[2 * HC + i * HC + j];
        const float mx = fmaxf(fmaxf(l[0], l[1]), fmaxf(l[2], l[3]));
        float e[HC];
        float sum = 0.0f;
        #pragma unroll
        for (int j = 0; j < HC; ++j) { e[j] = expf(l[j] - mx); sum += e[j]; }
        const float inv = 1.0f / sum;
        #pragma unroll
        for (int j = 0; j < HC; ++j) c[i][j] = e[j] * inv + HC_EPS;
    }
    #pragma unroll
    for (int j = 0; j < HC; ++j) {
        const float cs = c[0][j] + c[1][j] + c[2][j] + c[3][j] + HC_EPS;
        const float inv = 1.0f / cs;
        c[0][j] *= inv; c[1][j] *= inv; c[2][j] *= inv; c[3][j] *= inv;
    }
    #pragma unroll
    for (int it = 0; it < 4; ++it) {
        #pragma unroll
        for (int i = 0; i < HC; ++i) {
            const float rsum = c[i][0] + c[i][1] + c[i][2] + c[i][3] + HC_EPS;
            const float inv = 1.0f / rsum;
            c[i][0] *= inv; c[i][1] *= inv; c[i][2] *= inv; c[i][3] *= inv;
        }
        #pragma unroll
        for (int j = 0; j < HC; ++j) {
            const float cs = c[0][j] + c[1][j] + c[2][j] + c[3][j] + HC_EPS;
            const float inv = 1.0f / cs;
            c[0][j] *= inv; c[1][j] *= inv; c[2][j] *= inv; c[3][j] *= inv;
        }
    }
    #pragma unroll
    for (int i = 0; i < HC; ++i)
        #pragma unroll
        for (int j = 0; j < HC; ++j)
            out[COMB_OFF + r * (HC * HC) + i * HC + j] = c[i][j];
}

extern "C" void kernel_launch(void* const* d_in, const int* in_sizes, int n_in,
                              void* d_out, int out_size, void* d_ws, size_t ws_size,
                              hipStream_t stream) {
    const float* hs    = (const float*)d_in[0];
    const float* fn    = (const float*)d_in[1];
    const float* base  = (const float*)d_in[2];
    const float* scale = (const float*)d_in[3];
    float* out = (float*)d_out;
    float* ws  = (float*)d_ws;   // 512*16*16*25*4 B = 13.1 MB

    hyper_k1<<<KSPLIT * NSTREAM, THREADS1, 0, stream>>>(hs, fn, ws);
    hyper_k2<<<NROWS / 256, 256, 0, stream>>>(ws, base, scale, out);
}

// Round 14
// 139.182 us; speedup vs baseline: 1.0607x; 1.0607x over previous
//
#include <hip/hip_runtime.h>
#include <hip/hip_bf16.h>
#include <math.h>
#include <stdint.h>

#define HC 4
#define DIM 16384                  // hc*hidden
#define MIXN 24
#define NROWS 8192                 // B*S
#define KSPLIT 16                  // k-slices
#define KSL 1024                   // k per slice
#define NSTEPS 32                  // MFMA k-steps per slice
#define NSTREAM 32                 // row streams
#define ROWS_PER_STREAM 256
#define NTILES 16                  // 16-row tiles per block
#define THREADS1 512
#define HC_EPS 1e-5f
#define NORM_EPS 1e-6f

#define PRE_OFF 0
#define POST_OFF (NROWS * HC)
#define COMB_OFF (2 * NROWS * HC)

typedef float f32x4 __attribute__((ext_vector_type(4)));
typedef float accf4 __attribute__((ext_vector_type(4)));
typedef short bf16x8 __attribute__((ext_vector_type(8)));
typedef short bf16x4 __attribute__((ext_vector_type(4)));

__device__ __forceinline__ short f2bf(float x) {
    union { __hip_bfloat16 h; short s; } u;
    u.h = __float2bfloat16(x);
    return u.s;
}

// ---------------- kernel 1 ----------------
// All HBM A-traffic is 1KB-contiguous per wave instruction (one row chunk),
// fixing the DRAM-efficiency loss of the scattered fragment gather (R12/13:
// 3.7 TB/s). A goes regs -> bf16 -> swizzled fragment-layout LDS; fn stays
// resident in LDS; waves split K over a 16-row tile; per-tile LDS reduction.
__global__ __launch_bounds__(THREADS1) void hyper_k1(
    const float* __restrict__ hs,   // [NROWS][DIM]
    const float* __restrict__ fn,   // [MIXN][DIM]
    float* __restrict__ ws)         // [512 rowtiles][16 ks][16][25]
{
    const int tid  = threadIdx.x;
    const int wave = tid >> 6;
    const int lane = tid & 63;
    const int l15  = lane & 15;
    const int kg   = lane >> 4;
    const int ks     = blockIdx.x & (KSPLIT - 1);
    const int stream = blockIdx.x >> 4;

    __shared__ __align__(16) short s_fn[2][NSTEPS][512];  // 64 KB B-fragments
    __shared__ __align__(16) short s_a[2][NSTEPS][512];   // 64 KB A dbuf (fragment layout)
    __shared__ float sC[8][400];                          // 12.8 KB per-wave partials

    // ---- fill s_fn (R13-validated fast fill) ----
    #pragma unroll 1
    for (int p = 0; p < 8; ++p) {
        const int idx  = p * THREADS1 + tid;
        const int kgf  = idx & 3;
        const int s    = (idx >> 2) & 31;
        const int c    = (idx >> 7) & 15;
        const int tile = idx >> 11;
        const int col  = tile ? (c + 8) : c;
        const float* g = fn + (size_t)col * DIM + ks * KSL + s * 32 + kgf * 8;
        const f32x4 v0 = *(const f32x4*)g;
        const f32x4 v1 = *(const f32x4*)(g + 4);
        bf16x8 b = { f2bf(v0.x), f2bf(v0.y), f2bf(v0.z), f2bf(v0.w),
                     f2bf(v1.x), f2bf(v1.y), f2bf(v1.z), f2bf(v1.w) };
        *(bf16x8*)&s_fn[tile][s][(kgf * 16 + c) * 8] = b;
    }
    __syncthreads();

    // stage-lane decomposition: lane covers floats [l*4, l*4+4) of a 256-fl chunk
    const int st_slo = lane >> 3;          // s offset within chunk (j*8 + st_slo)
    const int st_kg  = (lane >> 1) & 3;
    const int st_e   = (lane & 1) * 4;     // element 0 or 4 within fragment-8
    const int sr0 = 2 * wave, sr1 = 2 * wave + 1;   // tile rows staged by this wave

    f32x4 R0, R1, R2, R3, R4, R5, R6, R7;

#define ISSUE(T) do { \
    const float* g0 = hs + (size_t)(stream * ROWS_PER_STREAM + (T) * 16 + sr0) * DIM + ks * KSL; \
    const float* g1 = hs + (size_t)(stream * ROWS_PER_STREAM + (T) * 16 + sr1) * DIM + ks * KSL; \
    R0 = *(const f32x4*)(g0 +   0 + lane * 4); \
    R1 = *(const f32x4*)(g0 + 256 + lane * 4); \
    R2 = *(const f32x4*)(g0 + 512 + lane * 4); \
    R3 = *(const f32x4*)(g0 + 768 + lane * 4); \
    R4 = *(const f32x4*)(g1 +   0 + lane * 4); \
    R5 = *(const f32x4*)(g1 + 256 + lane * 4); \
    R6 = *(const f32x4*)(g1 + 512 + lane * 4); \
    R7 = *(const f32x4*)(g1 + 768 + lane * 4); \
} while (0)

    // write one staged reg into fragment-layout LDS, XOR-swizzled by (s&7)<<4
#define WR1(B, Rj, r, j) do { \
    const int s_ = (j) * 8 + st_slo; \
    int byte_ = ((s_ * 64 + st_kg * 16 + (r)) * 16) + st_e * 2; \
    byte_ ^= ((s_ & 7) << 4); \
    bf16x4 v_ = { f2bf(Rj.x), f2bf(Rj.y), f2bf(Rj.z), f2bf(Rj.w) }; \
    *(bf16x4*)((char*)(&s_a[B][0][0]) + byte_) = v_; \
} while (0)

#define WRALL(B) do { \
    WR1(B, R0, sr0, 0); WR1(B, R1, sr0, 1); WR1(B, R2, sr0, 2); WR1(B, R3, sr0, 3); \
    WR1(B, R4, sr1, 0); WR1(B, R5, sr1, 1); WR1(B, R6, sr1, 2); WR1(B, R7, sr1, 3); \
} while (0)

    // prologue: tile 0 staged synchronously, tile 1 issued
    ISSUE(0);
    asm volatile("s_waitcnt vmcnt(0)" ::: "memory");
    WRALL(0);
    ISSUE(1);

    #pragma unroll 1
    for (int t = 0; t < NTILES; ++t) {
        const int buf = t & 1;
        asm volatile("s_waitcnt lgkmcnt(0)" ::: "memory");
        __builtin_amdgcn_s_barrier();            // raw: in-flight loads survive
        __builtin_amdgcn_sched_barrier(0);

        // ---- compute: this wave's 4 k-steps of the 16-row tile ----
        accf4 acc0 = {0.f, 0.f, 0.f, 0.f};
        accf4 acc1 = {0.f, 0.f, 0.f, 0.f};
        accf4 accS = {0.f, 0.f, 0.f, 0.f};
        #pragma unroll
        for (int i = 0; i < 4; ++i) {
            const int s = wave * 4 + i;
            int ab = ((s * 64 + lane) * 16) ^ ((s & 7) << 4);
            const bf16x8 af = *(const bf16x8*)((const char*)(&s_a[buf][0][0]) + ab);
            const bf16x8 b0 = *(const bf16x8*)&s_fn[0][s][lane * 8];
            const bf16x8 b1 = *(const bf16x8*)&s_fn[1][s][lane * 8];
            acc0 = __builtin_amdgcn_mfma_f32_16x16x32_bf16(af, b0, acc0, 0, 0, 0);
            acc1 = __builtin_amdgcn_mfma_f32_16x16x32_bf16(af, b1, acc1, 0, 0, 0);
            accS = __builtin_amdgcn_mfma_f32_16x16x32_bf16(af, af, accS, 0, 0, 0);
        }

        // per-wave partials -> sC (C layout validated R11)
        #pragma unroll
        for (int i = 0; i < 4; ++i)
            sC[wave][(kg * 4 + i) * 25 + l15] = acc0[i];
        if (l15 >= 8) {
            #pragma unroll
            for (int i = 0; i < 4; ++i)
                sC[wave][(kg * 4 + i) * 25 + l15 + 8] = acc1[i];
        }
        #pragma unroll
        for (int i = 0; i < 4; ++i)
            if (l15 == kg * 4 + i) sC[wave][l15 * 25 + 24] = accS[i];

        asm volatile("s_waitcnt lgkmcnt(0)" ::: "memory");
        __builtin_amdgcn_s_barrier();
        __builtin_amdgcn_sched_barrier(0);

        // ---- reduce 8 waves + store partial for (rowtile, ks) ----
        if (tid < 400) {
            const float v = sC[0][tid] + sC[1][tid] + sC[2][tid] + sC[3][tid]
                          + sC[4][tid] + sC[5][tid] + sC[6][tid] + sC[7][tid];
            ws[((size_t)(stream * NTILES + t) * KSPLIT + ks) * 400 + tid] = v;
        }

        // ---- stage tile t+1 (loads issued last iter), issue t+2 ----
        if (t + 1 < NTILES) {
            // vmcnt(1): wait the 8 loads of tile t+1, leave the ws store in flight
            asm volatile("s_waitcnt vmcnt(1)" ::: "memory");
            WRALL((t + 1) & 1);
            if (t + 2 < NTILES) ISSUE(t + 2);
        }
    }
#undef ISSUE
#undef WR1
#undef WRALL
}

// ---------------- kernel 2: reduce k-slices + epilogue ----------------
__global__ __launch_bounds__(256) void hyper_k2(
    const float* __restrict__ ws,
    const float* __restrict__ base,
    const float* __restrict__ scale,
    float* __restrict__ out)
{
    const int r  = blockIdx.x * 256 + threadIdx.x;   // row 0..8191
    const int rt = r >> 4, rr = r & 15;

    float v[25];
    #pragma unroll
    for (int c = 0; c < 25; ++c) v[c] = 0.f;
    #pragma unroll 1
    for (int ks = 0; ks < KSPLIT; ++ks) {
        const float* w = ws + (size_t)(rt * KSPLIT + ks) * 400 + rr * 25;
        #pragma unroll
        for (int c = 0; c < 25; ++c) v[c] += w[c];
    }

    const float rs = 1.0f / sqrtf(v[24] * (1.0f / (float)DIM) + NORM_EPS);
    const float s0 = scale[0], s1 = scale[1], s2 = scale[2];

    #pragma unroll
    for (int i = 0; i < HC; ++i) {
        const float z = v[i] * rs * s0 + base[i];
        out[PRE_OFF + r * HC + i] = 1.0f / (1.0f + expf(-z)) + HC_EPS;
    }
    #pragma unroll
    for (int i = 0; i < HC; ++i) {
        const float z = v[HC + i] * rs * s1 + base[HC + i];
        out[POST_OFF + r * HC + i] = 2.0f / (1.0f + expf(-z));
    }

    float c[HC][HC];
    #pragma unroll
    for (int i = 0; i < HC; ++i) {
        float l[HC];
        #pragma unroll
        for (int j = 0; j < HC; ++j)
            l[j] = v[2 * HC + i * HC + j] * rs * s2 + base[2 * HC + i * HC + j];
        const float mx = fmaxf(fmaxf(l[0], l[1]), fmaxf(l[2], l[3]));
        float e[HC];
        float sum = 0.0f;
        #pragma unroll
        for (int j = 0; j < HC; ++j) { e[j] = expf(l[j] - mx); sum += e[j]; }
        const float inv = 1.0f / sum;
        #pragma unroll
        for (int j = 0; j < HC; ++j) c[i][j] = e[j] * inv + HC_EPS;
    }
    #pragma unroll
    for (int j = 0; j < HC; ++j) {
        const float cs = c[0][j] + c[1][j] + c[2][j] + c[3][j] + HC_EPS;
        const float inv = 1.0f / cs;
        c[0][j] *= inv; c[1][j] *= inv; c[2][j] *= inv; c[3][j] *= inv;
    }
    #pragma unroll
    for (int it = 0; it < 4; ++it) {
        #pragma unroll
        for (int i = 0; i < HC; ++i) {
            const float rsum = c[i][0] + c[i][1] + c[i][2] + c[i][3] + HC_EPS;
            const float inv = 1.0f / rsum;
            c[i][0] *= inv; c[i][1] *= inv; c[i][2] *= inv; c[i][3] *= inv;
        }
        #pragma unroll
        for (int j = 0; j < HC; ++j) {
            const float cs = c[0][j] + c[1][j] + c[2][j] + c[3][j] + HC_EPS;
            const float inv = 1.0f / cs;
            c[0][j] *= inv; c[1][j] *= inv; c[2][j] *= inv; c[3][j] *= inv;
        }
    }
    #pragma unroll
    for (int i = 0; i < HC; ++i)
        #pragma unroll
        for (int j = 0; j < HC; ++j)
            out[COMB_OFF + r * (HC * HC) + i * HC + j] = c[i][j];
}

extern "C" void kernel_launch(void* const* d_in, const int* in_sizes, int n_in,
                              void* d_out, int out_size, void* d_ws, size_t ws_size,
                              hipStream_t stream) {
    const float* hs    = (const float*)d_in[0];
    const float* fn    = (const float*)d_in[1];
    const float* base  = (const float*)d_in[2];
    const float* scale = (const float*)d_in[3];
    float* out = (float*)d_out;
    float* ws  = (float*)d_ws;   // 512*16*400*4 B = 13.1 MB

    hyper_k1<<<KSPLIT * NSTREAM, THREADS1, 0, stream>>>(hs, fn, ws);
    hyper_k2<<<NROWS / 256, 256, 0, stream>>>(ws, base, scale, out);
}